// Round 7
// baseline (1008.755 us; speedup 1.0000x reference)
//
#include <hip/hip_runtime.h>
#include <math.h>

// Problem constants (fixed by the reference)
#define BN 256     // batch N
#define TT 1000    // timesteps
#define NO 10      // obs dim
#define NS 10      // state dim
#define HID 64     // GRU hidden == wavefront size
#define DIN 20     // NO + NS
#define G3 192     // 3*HID
#define GS 8       // steps per input group (1000 = 125 * 8)
#define NG 125     // groups

__device__ __forceinline__ float rcpf(float x) { return __builtin_amdgcn_rcpf(x); }
// broadcast lane l of v as raw bits (uniform -> SGPR)
__device__ __forceinline__ int rlb(float v, int l) {
    return __builtin_amdgcn_readlane(__float_as_int(v), l);
}
__device__ __forceinline__ unsigned short f2h(float f) {   // RNE f32->f16
    _Float16 h = (_Float16)f;
    union { _Float16 h; unsigned short u; } c; c.h = h; return c.u;
}
__device__ __forceinline__ unsigned pkh(float lo, float hi) {
    return (unsigned)f2h(lo) | ((unsigned)f2h(hi) << 16);
}

// v_fma_mix_f32: acc += src0(f32) * src1(f16 half); op_sel_hi[1]=1 marks src1
// as f16, op_sel[1] picks the half. src0 from SGPR (h broadcast) or VGPR (x).
#define MIXS_LO(acc, s0, wp) asm("v_fma_mix_f32 %0, %1, %2, %0 op_sel_hi:[0,1,0]" : "+v"(acc) : "s"(s0), "v"(wp))
#define MIXS_HI(acc, s0, wp) asm("v_fma_mix_f32 %0, %1, %2, %0 op_sel:[0,1,0] op_sel_hi:[0,1,0]" : "+v"(acc) : "s"(s0), "v"(wp))
#define MIXV_LO(acc, v0, wp) asm("v_fma_mix_f32 %0, %1, %2, %0 op_sel_hi:[0,1,0]" : "+v"(acc) : "v"(v0), "v"(wp))
#define MIXV_HI(acc, v0, wp) asm("v_fma_mix_f32 %0, %1, %2, %0 op_sel:[0,1,0] op_sel_hi:[0,1,0]" : "+v"(acc) : "v"(v0), "v"(wp))

// ---------------- Phase 1: GRU, ONE WAVE PER SAMPLE, NO BARRIER ------------
// R7 ledger: every barrier-synced config pays ~600-850 cy/step of rendezvous
// overhead (R0 1240, R7 1594, R5 1412, R6 1452 vs issue models); the one
// barrier-free config (R1, 2312) matches pure issue -- it lost only to VGPR
// overflow (350 demand > 256 addressable -> AGPR parking, ~600 unpark/step).
// Fix: f16-PACKED weights via v_fma_mix_f32 (2 weights/VGPR, same inst
// count, f32 accumulate). Demand ~210 VGPR -> addressable, no parking.
// h never leaves the wave (readlane broadcast); no LDS exchange, no barrier.
// f16 weights (11-bit mantissa) are strictly more accurate than the
// bf16 weights+state that already passed in R5/R6.
__global__
__attribute__((amdgpu_flat_work_group_size(64, 64), amdgpu_waves_per_eu(1, 1)))
void gru_onewave(const float* __restrict__ Yi, const float* __restrict__ Xh,
                 const float* __restrict__ Wi, const float* __restrict__ Wh,
                 const float* __restrict__ bi, const float* __restrict__ bh,
                 const float* __restrict__ Wmu, const float* __restrict__ Wvar,
                 float* __restrict__ mv_out) {
    const int lane = threadIdx.x;   // hidden unit index
    const int n = blockIdx.x;       // sample

    // input staging: [buf][step][32] floats; y at 0..9, x at 10..19, pad to 32
    // => 128 B rows, 16B-aligned float4 broadcast reads. Single wave: DS pipe
    // is in-order, so no barrier between staging writes and reads.
    __shared__ __align__(16) float inb[2][GS * 32];

    // ---- packed f16 weight pairs (k=2j lo, k=2j+1 hi), register-resident --
    unsigned whp_r[32], whp_z[32], whp_n[32], wmp[32];
#pragma unroll
    for (int j = 0; j < 32; ++j) {
        const int k0 = 2 * j, k1 = 2 * j + 1;
        whp_r[j] = pkh(Wh[k0 * G3 + lane],       Wh[k1 * G3 + lane]);
        whp_z[j] = pkh(Wh[k0 * G3 + 64 + lane],  Wh[k1 * G3 + 64 + lane]);
        whp_n[j] = pkh(Wh[k0 * G3 + 128 + lane], Wh[k1 * G3 + 128 + lane]);
        float m0 = 0.f, m1 = 0.f;
        if (lane < NS)        { m0 = Wmu[k0 * NS + lane];        m1 = Wmu[k1 * NS + lane]; }
        else if (lane < DIN)  { m0 = Wvar[k0 * NS + lane - NS];  m1 = Wvar[k1 * NS + lane - NS]; }
        wmp[j] = pkh(m0, m1);   // packed: lanes 0..9 W_mu, 10..19 W_var
    }
    unsigned wip_r[10], wip_z[10], wip_n[10];
#pragma unroll
    for (int j = 0; j < 10; ++j) {
        const int d0 = 2 * j, d1 = 2 * j + 1;
        wip_r[j] = pkh(Wi[d0 * G3 + lane],       Wi[d1 * G3 + lane]);
        wip_z[j] = pkh(Wi[d0 * G3 + 64 + lane],  Wi[d1 * G3 + 64 + lane]);
        wip_n[j] = pkh(Wi[d0 * G3 + 128 + lane], Wi[d1 * G3 + 128 + lane]);
    }
    const float b_r = bi[lane] + bh[lane];
    const float b_z = bi[64 + lane] + bh[64 + lane];
    const float bxn = bi[128 + lane];
    const float bhn = bh[128 + lane];

    const float* yb = Yi + (size_t)n * TT * NO;
    const float* xb = Xh + (size_t)n * TT * NS;
    float* ob = mv_out + (size_t)n * TT * DIN;

    // staging write addresses: flat input idx f -> step f/10, elem f%10
    const int s0i = lane / 10, j0 = lane - 10 * s0i;               // f = lane
    const int s1i = (64 + lane) / 10, j1 = (64 + lane) - 10 * s1i; // f = 64+lane
    const int wy0 = s0i * 32 + j0, wx0 = wy0 + 10;
    const int wy1 = s1i * 32 + j1, wx1 = wy1 + 10;

    // prologue: group 0 loads into registers
    float ly0 = yb[lane], lx0 = xb[lane];
    float ly1 = 0.0f, lx1 = 0.0f;
    if (lane < 16) { ly1 = yb[64 + lane]; lx1 = xb[64 + lane]; }

    float h = 0.0f;

#pragma unroll 1
    for (int g = 0; g < NG; ++g) {
        float* buf = inb[g & 1];
        // stage current group (writes precede this group's reads; DS in-order)
        buf[wy0] = ly0; buf[wx0] = lx0;
        if (lane < 16) { buf[wy1] = ly1; buf[wx1] = lx1; }
        // prefetch next group; 8 steps (~8k cycles) of latency cover
        if (g + 1 < NG) {
            const size_t o = (size_t)(g + 1) * (GS * NO);
            ly0 = yb[o + lane]; lx0 = xb[o + lane];
            if (lane < 16) { ly1 = yb[o + 64 + lane]; lx1 = xb[o + 64 + lane]; }
        }

#pragma unroll 2
        for (int s = 0; s < GS; ++s) {
            // x_t broadcast: 5 same-address ds_read_b128 (conflict-free)
            const float4* qp = (const float4*)(buf + s * 32);
            const float4 q0 = qp[0], q1 = qp[1], q2 = qp[2], q3 = qp[3], q4 = qp[4];

            float ar = b_r, az = b_z, ax = bxn, ah = bhn, am = 0.0f;

            // hidden + mv projections: h_{t-1} broadcast via readlane (SGPR),
            // f16-packed weights, 2 k's per j
#pragma unroll
            for (int j = 0; j < 32; ++j) {
                const int h0 = rlb(h, 2 * j);
                MIXS_LO(ar, h0, whp_r[j]);
                MIXS_LO(az, h0, whp_z[j]);
                MIXS_LO(ah, h0, whp_n[j]);
                MIXS_LO(am, h0, wmp[j]);
                const int h1 = rlb(h, 2 * j + 1);
                MIXS_HI(ar, h1, whp_r[j]);
                MIXS_HI(az, h1, whp_z[j]);
                MIXS_HI(ah, h1, whp_n[j]);
                MIXS_HI(am, h1, wmp[j]);
            }

            // input projection (x values broadcast-identical across lanes)
#define INP(j, xlo, xhi)                                        \
            MIXV_LO(ar, xlo, wip_r[j]);                         \
            MIXV_LO(az, xlo, wip_z[j]);                         \
            MIXV_LO(ax, xlo, wip_n[j]);                         \
            MIXV_HI(ar, xhi, wip_r[j]);                         \
            MIXV_HI(az, xhi, wip_z[j]);                         \
            MIXV_HI(ax, xhi, wip_n[j]);
            INP(0, q0.x, q0.y) INP(1, q0.z, q0.w)
            INP(2, q1.x, q1.y) INP(3, q1.z, q1.w)
            INP(4, q2.x, q2.y) INP(5, q2.z, q2.w)
            INP(6, q3.x, q3.y) INP(7, q3.z, q3.w)
            INP(8, q4.x, q4.y) INP(9, q4.z, q4.w)
#undef INP

            // amv computed this step is for t-1 (broadcasts were h_{t-1});
            // masked coalesced 80B store, stays in flight
            const int t = g * GS + s;
            if (t > 0 && lane < DIN) ob[(size_t)(t - 1) * DIN + lane] = am;

            // nonlinearity (identical numerics to the verified kernels)
            const float r = rcpf(1.0f + __expf(-ar));
            const float z = rcpf(1.0f + __expf(-az));
            const float pre = fmaf(r, ah, ax);
            const float e2 = __expf(2.0f * pre);    // inf-safe: nn -> +/-1
            const float nn = 1.0f - 2.0f * rcpf(e2 + 1.0f);
            h = fmaf(z, h - nn, nn);                // (1-z)*n + z*h
        }
    }

    // epilogue: amv for t = 999 from h_999
    {
        float am = 0.0f;
#pragma unroll
        for (int j = 0; j < 32; ++j) {
            const int h0 = rlb(h, 2 * j);
            MIXS_LO(am, h0, wmp[j]);
            const int h1 = rlb(h, 2 * j + 1);
            MIXS_HI(am, h1, wmp[j]);
        }
        if (lane < DIN) ob[(size_t)(TT - 1) * DIN + lane] = am;
    }
}

// ---------------- d_out init: the constant term ----------------------------
__global__ void init_out(float* out) {
    // -0.5*NO*T*log(2pi) / (T*NO) = -0.5*log(2pi)
    out[0] = -0.918938533204672742f;
}

// ---------------- Phase 2: per-(n,t) Gaussian log-lik (unchanged) ----------
__global__ __launch_bounds__(256)
void lik_phase2(const float* __restrict__ Yi, const float* __restrict__ Cw,
                const float* __restrict__ Hm, const float* __restrict__ mu_w,
                const float* __restrict__ b_mu, const float* __restrict__ b_var,
                const float* __restrict__ mv_in, float* __restrict__ out) {
    __shared__ float sH[NO * NS];
    __shared__ float smw[NO], sbm[NS], sbv[NS];
    __shared__ float ssum[4];
    const int tid = threadIdx.x;
    if (tid < NO * NS) sH[tid] = Hm[tid];
    if (tid < NO) smw[tid] = mu_w[tid];
    if (tid < NS) { sbm[tid] = b_mu[tid]; sbv[tid] = b_var[tid]; }
    __syncthreads();

    const int gid = blockIdx.x * 256 + tid;   // 0 .. BN*TT-1
    float contrib = 0.0f;
    if (gid < BN * TT) {
        const int n = gid / TT;
        const float* mv = mv_in + (size_t)gid * DIN;
        float mu[NS], va[NS];
#pragma unroll
        for (int i = 0; i < NS; ++i) {
            mu[i] = mv[i] + sbm[i];
            float x = mv[NS + i] + sbv[i];
            va[i] = (x > 0.0f) ? (x + log1pf(__expf(-x))) : log1pf(__expf(x));
        }
        const float* y = Yi + (size_t)gid * NO;
        float e[NO];
#pragma unroll
        for (int i = 0; i < NO; ++i) {
            float m = smw[i];
#pragma unroll
            for (int j = 0; j < NS; ++j) m = fmaf(sH[i * NS + j], mu[j], m);
            e[i] = y[i] - m;
        }
        // M = H diag(va) H^T + Cw (lower triangle only)
        float M[NO][NO];
        const float* cw = Cw + (size_t)n * NO * NO;
#pragma unroll
        for (int i = 0; i < NO; ++i)
#pragma unroll
            for (int j = 0; j <= i; ++j) M[i][j] = cw[i * NO + j];
#pragma unroll
        for (int l = 0; l < NS; ++l) {
            float vl = va[l];
            float hv[NO];
#pragma unroll
            for (int i = 0; i < NO; ++i) hv[i] = sH[i * NS + l];
#pragma unroll
            for (int i = 0; i < NO; ++i) {
                float hvi = hv[i] * vl;
#pragma unroll
                for (int j = 0; j <= i; ++j) M[i][j] = fmaf(hvi, hv[j], M[i][j]);
            }
        }
        // in-place Cholesky (lower); fast rsqrt/rcp (error ~1ulp, harmless
        // vs the 3.1e-2 threshold on an averaged scalar)
        float logdet = 0.0f;
        float drs[NO];
#pragma unroll
        for (int j = 0; j < NO; ++j) {
            float d = M[j][j];
#pragma unroll
            for (int k = 0; k < j; ++k) d = fmaf(-M[j][k], M[j][k], d);
            logdet += __logf(d);
            float rs = __frsqrt_rn(d);
            drs[j] = rs;
            M[j][j] = d * rs;
#pragma unroll
            for (int i = j + 1; i < NO; ++i) {
                float v = M[i][j];
#pragma unroll
                for (int k = 0; k < j; ++k) v = fmaf(-M[i][k], M[j][k], v);
                M[i][j] = v * rs;
            }
        }
        // quad = || L^-1 e ||^2 (forward solve)
        float wv[NO];
        float quad = 0.0f;
#pragma unroll
        for (int i = 0; i < NO; ++i) {
            float v = e[i];
#pragma unroll
            for (int k = 0; k < i; ++k) v = fmaf(-M[i][k], wv[k], v);
            wv[i] = v * drs[i] * rcpf(M[i][i] * drs[i]);  // v / M[i][i]
            quad = fmaf(wv[i], wv[i], quad);
        }
        const float SCALE = 0.5f / ((float)BN * (float)TT * (float)NO);
        contrib = -(logdet + quad) * SCALE;
    }

    // block reduction: wave shuffle, LDS across 4 waves, one atomic
#pragma unroll
    for (int off = 32; off > 0; off >>= 1) contrib += __shfl_down(contrib, off);
    if ((tid & 63) == 0) ssum[tid >> 6] = contrib;
    __syncthreads();
    if (tid == 0) {
        float s = ssum[0] + ssum[1] + ssum[2] + ssum[3];
        atomicAdd(out, s);
    }
}

// ---------------- launch ---------------------------------------------------
extern "C" void kernel_launch(void* const* d_in, const int* in_sizes, int n_in,
                              void* d_out, int out_size, void* d_ws, size_t ws_size,
                              hipStream_t stream) {
    const float* Yi    = (const float*)d_in[0];
    const float* Xh    = (const float*)d_in[1];
    const float* Cw    = (const float*)d_in[2];
    const float* Hm    = (const float*)d_in[3];
    const float* mu_w  = (const float*)d_in[4];
    const float* Wi    = (const float*)d_in[5];
    const float* Wh    = (const float*)d_in[6];
    const float* bi    = (const float*)d_in[7];
    const float* bh    = (const float*)d_in[8];
    const float* W_mu  = (const float*)d_in[9];
    const float* b_mu  = (const float*)d_in[10];
    const float* W_var = (const float*)d_in[11];
    const float* b_var = (const float*)d_in[12];
    float* out = (float*)d_out;
    float* mv  = (float*)d_ws;   // [BN*TT*DIN] floats = 20.48 MB

    init_out<<<1, 1, 0, stream>>>(out);
    gru_onewave<<<dim3(BN), dim3(64), 0, stream>>>(Yi, Xh, Wi, Wh, bi, bh,
                                                   W_mu, W_var, mv);
    lik_phase2<<<dim3((BN * TT + 255) / 256), dim3(256), 0, stream>>>(
        Yi, Cw, Hm, mu_w, b_mu, b_var, mv, out);
}

// Round 8
// 614.207 us; speedup vs baseline: 1.6424x; 1.6424x over previous
//
#include <hip/hip_runtime.h>
#include <math.h>

// Problem constants (fixed by the reference)
#define BN 256     // batch N
#define TT 1000    // timesteps
#define NO 10      // obs dim
#define NS 10      // state dim
#define HID 64     // GRU hidden == wavefront size
#define DIN 20     // NO + NS
#define G3 192     // 3*HID
#define GS 8       // steps per input group (1000 = 125 * 8)
#define NG 125     // groups

typedef _Float16 h2v __attribute__((ext_vector_type(2)));

__device__ __forceinline__ float rcpf(float x) { return __builtin_amdgcn_rcpf(x); }
__device__ __forceinline__ unsigned short f2h(float f) {   // RNE f32->f16
    _Float16 h = (_Float16)f;
    union { _Float16 h; unsigned short u; } c; c.h = h; return c.u;
}
__device__ __forceinline__ unsigned pk2(float lo, float hi) {
    return (unsigned)f2h(lo) | ((unsigned)f2h(hi) << 16);
}

// 2 MACs/inst: D = a.l*b.l + a.h*b.h + c  (f16 inputs, f32 accumulate)
#if __has_builtin(__builtin_amdgcn_fdot2)
__device__ __forceinline__ float dot2(unsigned a, unsigned b, float c) {
    return __builtin_amdgcn_fdot2(__builtin_bit_cast(h2v, a),
                                  __builtin_bit_cast(h2v, b), c, false);
}
#else
// fallback: two v_fma_mix_f32 (R7-verified encoding), both srcs f16
__device__ __forceinline__ float dot2(unsigned a, unsigned b, float c) {
    asm("v_fma_mix_f32 %0, %1, %2, %0 op_sel_hi:[1,1,0]" : "+v"(c) : "v"(a), "v"(b));
    asm("v_fma_mix_f32 %0, %1, %2, %0 op_sel:[1,1,0] op_sel_hi:[1,1,0]" : "+v"(c) : "v"(a), "v"(b));
    return c;
}
#endif

// ---------------- Phase 1: GRU, ONE WAVE PER SAMPLE, NO BARRIER ------------
// R8 ledger: barrier-free structure verified (R1/R7 pass); R7 measured
// 2218 cy/step, issue/hazard-bound (74.5% SIMD busy, ~826 inst-equiv vs
// ~420 designed; readlane->VALU SGPR hazard paid 64x/step, 1 inst/MAC).
// Fixes: (1) v_dot2_f32_f16 = 2 MACs/inst -> hidden+mv 128 dot2, input 30;
// (2) broadcast batching: cvt h->f16 once, DPP quad-swap + shift-or to form
// per-lane (h[2j],h[2j+1]) pairs, then 32 readlanes in ONE block (hazard
// distance >= 32 inst). Weights f16x2 (passed R7); h f16 (8x more precise
// than the bf16 h that passed R5/R6); accumulate f32.
__global__
__attribute__((amdgpu_flat_work_group_size(64, 64), amdgpu_waves_per_eu(1, 1)))
void gru_onewave(const float* __restrict__ Yi, const float* __restrict__ Xh,
                 const float* __restrict__ Wi, const float* __restrict__ Wh,
                 const float* __restrict__ bi, const float* __restrict__ bh,
                 const float* __restrict__ Wmu, const float* __restrict__ Wvar,
                 float* __restrict__ mv_out) {
    const int lane = threadIdx.x;   // hidden unit index
    const int n = blockIdx.x;       // sample

    // input staging: [buf][step][16 words] f16x2; word d = input dims
    // (2d, 2d+1), d = 0..9 (y dims 0..9 then x dims 10..19); 10..15 pad
    // (never read). 128B rows -> aligned b128/b64 broadcast reads.
    // Single wave: DS pipe in-order, no barrier between write and read.
    __shared__ __align__(16) unsigned inb[2][GS * 16];   // 1 KB

    // ---- packed f16 weight pairs (k=2j lo, 2j+1 hi), register-resident ----
    unsigned whp_r[32], whp_z[32], whp_n[32], wmp[32];
#pragma unroll
    for (int j = 0; j < 32; ++j) {
        const int k0 = 2 * j, k1 = 2 * j + 1;
        whp_r[j] = pk2(Wh[k0 * G3 + lane],       Wh[k1 * G3 + lane]);
        whp_z[j] = pk2(Wh[k0 * G3 + 64 + lane],  Wh[k1 * G3 + 64 + lane]);
        whp_n[j] = pk2(Wh[k0 * G3 + 128 + lane], Wh[k1 * G3 + 128 + lane]);
        float m0 = 0.f, m1 = 0.f;
        if (lane < NS)        { m0 = Wmu[k0 * NS + lane];        m1 = Wmu[k1 * NS + lane]; }
        else if (lane < DIN)  { m0 = Wvar[k0 * NS + lane - NS];  m1 = Wvar[k1 * NS + lane - NS]; }
        wmp[j] = pk2(m0, m1);   // packed: lanes 0..9 W_mu, 10..19 W_var
    }
    unsigned wip_r[10], wip_z[10], wip_n[10];   // input dim-pairs (2d,2d+1)
#pragma unroll
    for (int d = 0; d < 10; ++d) {
        const int d0 = 2 * d, d1 = 2 * d + 1;
        wip_r[d] = pk2(Wi[d0 * G3 + lane],       Wi[d1 * G3 + lane]);
        wip_z[d] = pk2(Wi[d0 * G3 + 64 + lane],  Wi[d1 * G3 + 64 + lane]);
        wip_n[d] = pk2(Wi[d0 * G3 + 128 + lane], Wi[d1 * G3 + 128 + lane]);
    }
    const float b_r = bi[lane] + bh[lane];
    const float b_z = bi[64 + lane] + bh[64 + lane];
    const float bxn = bi[128 + lane];
    const float bhn = bh[128 + lane];

    const float* yb = Yi + (size_t)n * TT * NO;
    const float* xb = Xh + (size_t)n * TT * NS;
    float* ob = mv_out + (size_t)n * TT * DIN;

    // staging roles: word wd -> step wd/10, dim-pair wd%10 (pr<5: y, else x)
    const int st0 = lane / 10, pr0 = lane % 10;              // wd = lane
    const float* sb0 = (pr0 < 5) ? yb : xb;
    const int of0 = st0 * 10 + 2 * (pr0 % 5);
    const int sl0 = st0 * 16 + pr0;
    const int wd1 = 64 + lane;                               // lane<16
    const int st1 = wd1 / 10, pr1 = wd1 % 10;
    const float* sb1 = (pr1 < 5) ? yb : xb;
    const int of1 = st1 * 10 + 2 * (pr1 % 5);
    const int sl1 = st1 * 16 + pr1;

    // prologue: group 0 loads into registers (packed to f16x2)
    unsigned pk0, pk1 = 0;
    {
        const float2 v0 = *(const float2*)(sb0 + of0);
        pk0 = pk2(v0.x, v0.y);
        if (lane < 16) {
            const float2 v1 = *(const float2*)(sb1 + of1);
            pk1 = pk2(v1.x, v1.y);
        }
    }

    float h = 0.0f;

#pragma unroll 1
    for (int g = 0; g < NG; ++g) {
        unsigned* buf = inb[g & 1];
        // stage current group (writes precede this group's reads; DS in-order)
        buf[sl0] = pk0;
        if (lane < 16) buf[sl1] = pk1;
        // prefetch next group; ~8 steps of latency cover
        if (g + 1 < NG) {
            const size_t o = (size_t)(g + 1) * 80;
            const float2 v0 = *(const float2*)(sb0 + o + of0);
            pk0 = pk2(v0.x, v0.y);
            if (lane < 16) {
                const float2 v1 = *(const float2*)(sb1 + o + of1);
                pk1 = pk2(v1.x, v1.y);
            }
        }

#pragma unroll 2
        for (int s = 0; s < GS; ++s) {
            // x_t broadcast: words 0..9 as b128+b128+b64 same-address reads
            const unsigned* row = buf + s * 16;
            const uint4 qa = *(const uint4*)(row);
            const uint4 qb = *(const uint4*)(row + 4);
            const uint2 qc = *(const uint2*)(row + 8);

            // ---- batched h broadcast: pairs (h[2j],h[2j+1]) as f16x2 ----
            const unsigned h16 = (unsigned)f2h(h);
            const unsigned nb16 = (unsigned)__builtin_amdgcn_update_dpp(
                0, (int)h16, 0xB1 /*quad_perm [1,0,3,2]*/, 0xF, 0xF, true);
            const unsigned hp = h16 | (nb16 << 16);   // valid at even lanes
            int rl[32];
#pragma unroll
            for (int j = 0; j < 32; ++j)
                rl[j] = __builtin_amdgcn_readlane((int)hp, 2 * j);

            float ar = b_r, az = b_z, ax = bxn, ah = bhn, am = 0.0f;

            // hidden + mv: 32 k-pairs x 4 gates, 2 MACs each
#pragma unroll
            for (int j = 0; j < 32; ++j) {
                const unsigned hpj = (unsigned)rl[j];
                ar = dot2(hpj, whp_r[j], ar);
                az = dot2(hpj, whp_z[j], az);
                ah = dot2(hpj, whp_n[j], ah);
                am = dot2(hpj, wmp[j], am);
            }

            // input projection: 10 dim-pairs x 3 gates
#define INP(d, w)                                   \
            ar = dot2(w, wip_r[d], ar);             \
            az = dot2(w, wip_z[d], az);             \
            ax = dot2(w, wip_n[d], ax);
            INP(0, qa.x) INP(1, qa.y) INP(2, qa.z) INP(3, qa.w)
            INP(4, qb.x) INP(5, qb.y) INP(6, qb.z) INP(7, qb.w)
            INP(8, qc.x) INP(9, qc.y)
#undef INP

            // amv computed this step is for t-1 (broadcasts were h_{t-1});
            // masked coalesced 80B store, stays in flight
            const int t = g * GS + s;
            if (t > 0 && lane < DIN) ob[(size_t)(t - 1) * DIN + lane] = am;

            // nonlinearity (identical numerics to the verified kernels)
            const float r = rcpf(1.0f + __expf(-ar));
            const float z = rcpf(1.0f + __expf(-az));
            const float pre = fmaf(r, ah, ax);
            const float e2 = __expf(2.0f * pre);    // inf-safe: nn -> +/-1
            const float nn = 1.0f - 2.0f * rcpf(e2 + 1.0f);
            h = fmaf(z, h - nn, nn);                // (1-z)*n + z*h
        }
    }

    // epilogue: amv for t = 999 from h_999
    {
        const unsigned h16 = (unsigned)f2h(h);
        const unsigned nb16 = (unsigned)__builtin_amdgcn_update_dpp(
            0, (int)h16, 0xB1, 0xF, 0xF, true);
        const unsigned hp = h16 | (nb16 << 16);
        float am = 0.0f;
#pragma unroll
        for (int j = 0; j < 32; ++j) {
            const unsigned hpj = (unsigned)__builtin_amdgcn_readlane((int)hp, 2 * j);
            am = dot2(hpj, wmp[j], am);
        }
        if (lane < DIN) ob[(size_t)(TT - 1) * DIN + lane] = am;
    }
}

// ---------------- d_out init: the constant term ----------------------------
__global__ void init_out(float* out) {
    // -0.5*NO*T*log(2pi) / (T*NO) = -0.5*log(2pi)
    out[0] = -0.918938533204672742f;
}

// ---------------- Phase 2: per-(n,t) Gaussian log-lik (unchanged) ----------
__global__ __launch_bounds__(256)
void lik_phase2(const float* __restrict__ Yi, const float* __restrict__ Cw,
                const float* __restrict__ Hm, const float* __restrict__ mu_w,
                const float* __restrict__ b_mu, const float* __restrict__ b_var,
                const float* __restrict__ mv_in, float* __restrict__ out) {
    __shared__ float sH[NO * NS];
    __shared__ float smw[NO], sbm[NS], sbv[NS];
    __shared__ float ssum[4];
    const int tid = threadIdx.x;
    if (tid < NO * NS) sH[tid] = Hm[tid];
    if (tid < NO) smw[tid] = mu_w[tid];
    if (tid < NS) { sbm[tid] = b_mu[tid]; sbv[tid] = b_var[tid]; }
    __syncthreads();

    const int gid = blockIdx.x * 256 + tid;   // 0 .. BN*TT-1
    float contrib = 0.0f;
    if (gid < BN * TT) {
        const int n = gid / TT;
        const float* mv = mv_in + (size_t)gid * DIN;
        float mu[NS], va[NS];
#pragma unroll
        for (int i = 0; i < NS; ++i) {
            mu[i] = mv[i] + sbm[i];
            float x = mv[NS + i] + sbv[i];
            va[i] = (x > 0.0f) ? (x + log1pf(__expf(-x))) : log1pf(__expf(x));
        }
        const float* y = Yi + (size_t)gid * NO;
        float e[NO];
#pragma unroll
        for (int i = 0; i < NO; ++i) {
            float m = smw[i];
#pragma unroll
            for (int j = 0; j < NS; ++j) m = fmaf(sH[i * NS + j], mu[j], m);
            e[i] = y[i] - m;
        }
        // M = H diag(va) H^T + Cw (lower triangle only)
        float M[NO][NO];
        const float* cw = Cw + (size_t)n * NO * NO;
#pragma unroll
        for (int i = 0; i < NO; ++i)
#pragma unroll
            for (int j = 0; j <= i; ++j) M[i][j] = cw[i * NO + j];
#pragma unroll
        for (int l = 0; l < NS; ++l) {
            float vl = va[l];
            float hv[NO];
#pragma unroll
            for (int i = 0; i < NO; ++i) hv[i] = sH[i * NS + l];
#pragma unroll
            for (int i = 0; i < NO; ++i) {
                float hvi = hv[i] * vl;
#pragma unroll
                for (int j = 0; j <= i; ++j) M[i][j] = fmaf(hvi, hv[j], M[i][j]);
            }
        }
        // in-place Cholesky (lower); fast rsqrt/rcp (error ~1ulp, harmless
        // vs the 3.1e-2 threshold on an averaged scalar)
        float logdet = 0.0f;
        float drs[NO];
#pragma unroll
        for (int j = 0; j < NO; ++j) {
            float d = M[j][j];
#pragma unroll
            for (int k = 0; k < j; ++k) d = fmaf(-M[j][k], M[j][k], d);
            logdet += __logf(d);
            float rs = __frsqrt_rn(d);
            drs[j] = rs;
            M[j][j] = d * rs;
#pragma unroll
            for (int i = j + 1; i < NO; ++i) {
                float v = M[i][j];
#pragma unroll
                for (int k = 0; k < j; ++k) v = fmaf(-M[i][k], M[j][k], v);
                M[i][j] = v * rs;
            }
        }
        // quad = || L^-1 e ||^2 (forward solve)
        float wv[NO];
        float quad = 0.0f;
#pragma unroll
        for (int i = 0; i < NO; ++i) {
            float v = e[i];
#pragma unroll
            for (int k = 0; k < i; ++k) v = fmaf(-M[i][k], wv[k], v);
            wv[i] = v * drs[i] * rcpf(M[i][i] * drs[i]);  // v / M[i][i]
            quad = fmaf(wv[i], wv[i], quad);
        }
        const float SCALE = 0.5f / ((float)BN * (float)TT * (float)NO);
        contrib = -(logdet + quad) * SCALE;
    }

    // block reduction: wave shuffle, LDS across 4 waves, one atomic
#pragma unroll
    for (int off = 32; off > 0; off >>= 1) contrib += __shfl_down(contrib, off);
    if ((tid & 63) == 0) ssum[tid >> 6] = contrib;
    __syncthreads();
    if (tid == 0) {
        float s = ssum[0] + ssum[1] + ssum[2] + ssum[3];
        atomicAdd(out, s);
    }
}

// ---------------- launch ---------------------------------------------------
extern "C" void kernel_launch(void* const* d_in, const int* in_sizes, int n_in,
                              void* d_out, int out_size, void* d_ws, size_t ws_size,
                              hipStream_t stream) {
    const float* Yi    = (const float*)d_in[0];
    const float* Xh    = (const float*)d_in[1];
    const float* Cw    = (const float*)d_in[2];
    const float* Hm    = (const float*)d_in[3];
    const float* mu_w  = (const float*)d_in[4];
    const float* Wi    = (const float*)d_in[5];
    const float* Wh    = (const float*)d_in[6];
    const float* bi    = (const float*)d_in[7];
    const float* bh    = (const float*)d_in[8];
    const float* W_mu  = (const float*)d_in[9];
    const float* b_mu  = (const float*)d_in[10];
    const float* W_var = (const float*)d_in[11];
    const float* b_var = (const float*)d_in[12];
    float* out = (float*)d_out;
    float* mv  = (float*)d_ws;   // [BN*TT*DIN] floats = 20.48 MB

    init_out<<<1, 1, 0, stream>>>(out);
    gru_onewave<<<dim3(BN), dim3(64), 0, stream>>>(Yi, Xh, Wi, Wh, bi, bh,
                                                   W_mu, W_var, mv);
    lik_phase2<<<dim3((BN * TT + 255) / 256), dim3(256), 0, stream>>>(
        Yi, Cw, Hm, mu_w, b_mu, b_var, mv, out);
}